// Round 1
// baseline (719.019 us; speedup 1.0000x reference)
//
#include <hip/hip_runtime.h>
#include <hip/hip_bf16.h>
#include <math.h>

typedef __bf16 bf16_t;
typedef __bf16 bf16x4_t __attribute__((ext_vector_type(4)));
typedef __bf16 bf16x8_t __attribute__((ext_vector_type(8)));
typedef float  f32x4    __attribute__((ext_vector_type(4)));

#define NE  8
#define NR  16
#define ND  2048
#define NH  8192
#define NT  4096
#define NER 128              // NE*NR
#define NK1 (ND + NER)       // 2176
#define NK2 (NH + NER)       // 8320

static __device__ __forceinline__ float gelu_new_f(float x) {
    const float c0 = 0.7978845608028654f;  // sqrt(2/pi)
    return 0.5f * x * (1.0f + tanhf(c0 * (x + 0.044715f * x * x * x)));
}

// async global->LDS, 16B per lane; LDS dest is wave-uniform base + lane*16
static __device__ __forceinline__ void load16_to_lds(const bf16_t* g, bf16_t* l) {
    __builtin_amdgcn_global_load_lds(
        (__attribute__((address_space(1))) void*)(g),
        (__attribute__((address_space(3))) void*)(l),
        16, 0, 0);
}

// ---------------------------------------------------------------------------
// z1: per-token z = 2 * (x . A1[e,r,:]) masked into 128-wide lora block of
// Xaug1; also converts x -> bf16 into Xaug1[:, 0:ND]. One wave per token.
// ---------------------------------------------------------------------------
__global__ __launch_bounds__(256) void z1_kernel(
    const float* __restrict__ x, const int* __restrict__ eidx,
    const float* __restrict__ A1, bf16_t* __restrict__ Xa1)
{
    const int t    = blockIdx.x * 4 + (threadIdx.x >> 6);
    const int lane = threadIdx.x & 63;
    const int e    = eidx[t];
    const float* xr = x  + (long)t * ND;
    const float* Ae = A1 + (long)e * NR * ND;
    bf16_t* xo = Xa1 + (long)t * NK1;

    float acc[NR];
#pragma unroll
    for (int r = 0; r < NR; ++r) acc[r] = 0.f;

    for (int it = 0; it < ND / 256; ++it) {
        const int d = it * 256 + lane * 4;
        f32x4 xv = *(const f32x4*)(xr + d);
        bf16x4_t o = {(bf16_t)xv[0], (bf16_t)xv[1], (bf16_t)xv[2], (bf16_t)xv[3]};
        *(bf16x4_t*)(xo + d) = o;
#pragma unroll
        for (int r = 0; r < NR; ++r) {
            f32x4 av = *(const f32x4*)(Ae + (long)r * ND + d);
            acc[r] += xv[0]*av[0] + xv[1]*av[1] + xv[2]*av[2] + xv[3]*av[3];
        }
    }
#pragma unroll
    for (int r = 0; r < NR; ++r) {
#pragma unroll
        for (int off = 32; off > 0; off >>= 1)
            acc[r] += __shfl_xor(acc[r], off, 64);
    }
    // write masked 128-wide lora block (zeros except assigned expert's 16)
#pragma unroll
    for (int sI = 0; sI < 2; ++sI) {
        const int s = lane + sI * 64;
        float v = 0.f;
#pragma unroll
        for (int r = 0; r < NR; ++r) v = (s == e * NR + r) ? 2.0f * acc[r] : v;
        Xa1[(long)t * NK1 + ND + s] = (bf16_t)v;
    }
}

// ---------------------------------------------------------------------------
// z2: same, but y comes from Xaug2 (bf16), K=NH, writes Xaug2[:, NH:NH+128]
// ---------------------------------------------------------------------------
__global__ __launch_bounds__(256) void z2_kernel(
    const int* __restrict__ eidx, const float* __restrict__ A2,
    bf16_t* __restrict__ Xa2)
{
    const int t    = blockIdx.x * 4 + (threadIdx.x >> 6);
    const int lane = threadIdx.x & 63;
    const int e    = eidx[t];
    const bf16_t* yr = Xa2 + (long)t * NK2;
    const float*  Ae = A2  + (long)e * NR * NH;

    float acc[NR];
#pragma unroll
    for (int r = 0; r < NR; ++r) acc[r] = 0.f;

    for (int it = 0; it < NH / 256; ++it) {
        const int d = it * 256 + lane * 4;
        bf16x4_t yv = *(const bf16x4_t*)(yr + d);
        f32x4 xv = {(float)yv[0], (float)yv[1], (float)yv[2], (float)yv[3]};
#pragma unroll
        for (int r = 0; r < NR; ++r) {
            f32x4 av = *(const f32x4*)(Ae + (long)r * NH + d);
            acc[r] += xv[0]*av[0] + xv[1]*av[1] + xv[2]*av[2] + xv[3]*av[3];
        }
    }
#pragma unroll
    for (int r = 0; r < NR; ++r) {
#pragma unroll
        for (int off = 32; off > 0; off >>= 1)
            acc[r] += __shfl_xor(acc[r], off, 64);
    }
#pragma unroll
    for (int sI = 0; sI < 2; ++sI) {
        const int s = lane + sI * 64;
        float v = 0.f;
#pragma unroll
        for (int r = 0; r < NR; ++r) v = (s == e * NR + r) ? 2.0f * acc[r] : v;
        Xa2[(long)t * NK2 + NH + s] = (bf16_t)v;
    }
}

// ---------------------------------------------------------------------------
// weight repack: fp32 [nrows][K0] -> bf16 [nrows][K0+128] (main region)
// ---------------------------------------------------------------------------
__global__ __launch_bounds__(256) void prep_main(
    const float* __restrict__ W, bf16_t* __restrict__ Waug,
    int ld, int shift, int total4)
{
    const int i = blockIdx.x * 256 + threadIdx.x;
    if (i >= total4) return;
    const int row = i >> shift;
    const int c4  = i & ((1 << shift) - 1);
    f32x4 v = *(const f32x4*)(W + (long)i * 4);
    bf16x4_t o = {(bf16_t)v[0], (bf16_t)v[1], (bf16_t)v[2], (bf16_t)v[3]};
    *(bf16x4_t*)(Waug + (long)row * ld + (c4 << 2)) = o;
}

// lora region: Waug[row][K0 + e*16 + r] = Blora[e][row][r]
__global__ __launch_bounds__(256) void prep_lora(
    const float* __restrict__ Bl, bf16_t* __restrict__ Waug,
    int nrows, int K0, int ld, int total)
{
    const int i = blockIdx.x * 256 + threadIdx.x;
    if (i >= total) return;
    const int row = i >> 7;
    const int c   = i & 127;
    const int e   = c >> 4;
    const int r   = c & 15;
    float v = Bl[((long)e * nrows + row) * NR + r];
    Waug[(long)row * ld + K0 + c] = (bf16_t)v;
}

// ---------------------------------------------------------------------------
// m97-style bf16 GEMM: C[m][n] = sum_k A[m][k]*Bt[n][k] (+bias[n])
// 128x128 tile, BK=32, 4 waves in 2x2, 16x16x32 MFMA, global_load_lds w=16.
// MODE 0: gelu_new -> bf16 store to Xaug2 (ld NK2). MODE 1: fp32 store (ld ND).
// ---------------------------------------------------------------------------
template <int MODE>
__global__ __launch_bounds__(256) void gemm_bt(
    const bf16_t* __restrict__ A,  const bf16_t* __restrict__ Bt,
    const float* __restrict__ bias, void* __restrict__ Cout, int K)
{
    __shared__ bf16_t As[128 * 32];
    __shared__ bf16_t Bs[128 * 32];

    const int tid   = threadIdx.x;
    const int wave  = tid >> 6;
    const int lane  = tid & 63;
    const int col16 = lane & 15;
    const int q     = lane >> 4;
    const int wm    = wave & 1;
    const int wn    = wave >> 1;

    const int rowA0 = blockIdx.y * 128;
    const int colB0 = blockIdx.x * 128;

    // staging geometry: each global_load_lds: 64 lanes x 16B = 16 rows of 32-k
    const int srow  = lane >> 2;
    const int skoff = (lane & 3) * 8;
    const int r0a = wave * 32;        // chunk 0 rows
    const int r0b = wave * 32 + 16;   // chunk 1 rows

    const bf16_t* Ag0 = A  + (long)(rowA0 + r0a + srow) * K + skoff;
    const bf16_t* Ag1 = A  + (long)(rowA0 + r0b + srow) * K + skoff;
    const bf16_t* Bg0 = Bt + (long)(colB0 + r0a + srow) * K + skoff;
    const bf16_t* Bg1 = Bt + (long)(colB0 + r0b + srow) * K + skoff;
    bf16_t* AsD0 = &As[r0a * 32];
    bf16_t* AsD1 = &As[r0b * 32];
    bf16_t* BsD0 = &Bs[r0a * 32];
    bf16_t* BsD1 = &Bs[r0b * 32];

    f32x4 acc[4][4];
#pragma unroll
    for (int i = 0; i < 4; ++i)
#pragma unroll
        for (int j = 0; j < 4; ++j)
            acc[i][j] = (f32x4){0.f, 0.f, 0.f, 0.f};

    for (int k0 = 0; k0 < K; k0 += 32) {
        load16_to_lds(Ag0 + k0, AsD0);
        load16_to_lds(Ag1 + k0, AsD1);
        load16_to_lds(Bg0 + k0, BsD0);
        load16_to_lds(Bg1 + k0, BsD1);
        __syncthreads();   // drains vmcnt: tiles visible

        bf16x8_t af[4], bfr[4];
#pragma unroll
        for (int mt = 0; mt < 4; ++mt)
            af[mt] = *(const bf16x8_t*)&As[(wm * 64 + mt * 16 + col16) * 32 + q * 8];
#pragma unroll
        for (int nt = 0; nt < 4; ++nt)
            bfr[nt] = *(const bf16x8_t*)&Bs[(wn * 64 + nt * 16 + col16) * 32 + q * 8];

#pragma unroll
        for (int mt = 0; mt < 4; ++mt)
#pragma unroll
            for (int nt = 0; nt < 4; ++nt)
                acc[mt][nt] = __builtin_amdgcn_mfma_f32_16x16x32_bf16(
                    af[mt], bfr[nt], acc[mt][nt], 0, 0, 0);

        __syncthreads();   // all reads done before next stage overwrites
    }

    // epilogue: C/D layout col=lane&15, row=q*4+reg
#pragma unroll
    for (int nt = 0; nt < 4; ++nt) {
        const int col = colB0 + wn * 64 + nt * 16 + col16;
        const float bv = bias[col];
#pragma unroll
        for (int mt = 0; mt < 4; ++mt) {
            const int row0 = rowA0 + wm * 64 + mt * 16 + q * 4;
#pragma unroll
            for (int i = 0; i < 4; ++i) {
                const float v = acc[mt][nt][i] + bv;
                if (MODE == 0) {
                    ((bf16_t*)Cout)[(long)(row0 + i) * NK2 + col] =
                        (bf16_t)gelu_new_f(v);
                } else {
                    ((float*)Cout)[(long)(row0 + i) * ND + col] = v;
                }
            }
        }
    }
}

// ---------------------------------------------------------------------------
extern "C" void kernel_launch(void* const* d_in, const int* in_sizes, int n_in,
                              void* d_out, int out_size, void* d_ws, size_t ws_size,
                              hipStream_t stream)
{
    const float* x    = (const float*)d_in[0];
    const int*   eidx = (const int*)  d_in[1];
    const float* W1   = (const float*)d_in[2];
    const float* b1   = (const float*)d_in[3];
    const float* A1   = (const float*)d_in[4];
    const float* B1   = (const float*)d_in[5];
    const float* W2   = (const float*)d_in[6];
    const float* b2   = (const float*)d_in[7];
    const float* A2   = (const float*)d_in[8];
    const float* B2   = (const float*)d_in[9];
    float* out = (float*)d_out;

    // workspace carve (bytes):
    //   Xaug2 : [0, 68,157,440)                       NT*NK2*2
    //   Xaug1 : [68,157,440, 85,983,232)              NT*NK1*2
    //   W1aug : [85,983,232, 121,634,816)             NH*NK1*2
    //   W2aug : [68,157,440, 102,236,160)  -- reuses Xaug1/W1aug after GEMM1
    char* ws = (char*)d_ws;
    bf16_t* Xaug2 = (bf16_t*)(ws);
    bf16_t* Xaug1 = (bf16_t*)(ws + 68157440L);
    bf16_t* W1aug = (bf16_t*)(ws + 85983232L);
    bf16_t* W2aug = (bf16_t*)(ws + 68157440L);  // alias: Xaug1/W1aug dead by then

    // --- layer 1 prep ---
    z1_kernel<<<NT / 4, 256, 0, stream>>>(x, eidx, A1, Xaug1);
    prep_main<<<(NH * ND / 4) / 256, 256, 0, stream>>>(W1, W1aug, NK1, 9,  NH * ND / 4);
    prep_lora<<<(NH * NER) / 256, 256, 0, stream>>>(B1, W1aug, NH, ND, NK1, NH * NER);

    // --- GEMM1: h1 = Xaug1 @ W1aug^T + b1 ; y = gelu(h1) -> Xaug2[:,0:NH] ---
    {
        dim3 g(NH / 128, NT / 128);
        gemm_bt<0><<<g, 256, 0, stream>>>(Xaug1, W1aug, b1, (void*)Xaug2, NK1);
    }

    // --- layer 2 prep ---
    z2_kernel<<<NT / 4, 256, 0, stream>>>(eidx, A2, Xaug2);
    prep_main<<<(ND * NH / 4) / 256, 256, 0, stream>>>(W2, W2aug, NK2, 11, ND * NH / 4);
    prep_lora<<<(ND * NER) / 256, 256, 0, stream>>>(B2, W2aug, ND, NH, NK2, ND * NER);

    // --- GEMM2: out = Xaug2 @ W2aug^T + b2 (fp32) ---
    {
        dim3 g(ND / 128, NT / 128);
        gemm_bt<1><<<g, 256, 0, stream>>>(Xaug2, W2aug, b2, (void*)out, NK2);
    }
}